// Round 7
// baseline (195.624 us; speedup 1.0000x reference)
//
#include <hip/hip_runtime.h>
#include <stdint.h>

typedef int v4i  __attribute__((ext_vector_type(4)));

// Problem dims
#define N_IMG 32
#define C_IN 256
#define H_IN 56
#define W_IN 56
#define C_OUT 256
#define H_OUT 28
#define W_OUT 28
#define H_PAD 58
#define W_PAD 58
#define SP_TOT (N_IMG*H_OUT*W_OUT)   // 25088

#define XPAD_BYTES ((size_t)N_IMG*H_PAD*W_PAD*C_IN)   // 27,557,888 (16B aligned)

// NOTE: activations are stored in a PERMUTED channel order: stored position
// p holds original channel sigma(p) = 64*(p&3) + (p>>2). Weights use the
// same permutation on ci, so the conv's ci-sum is unchanged.

__device__ __forceinline__ void glds16(const int8_t* g, int8_t* l) {
    __builtin_amdgcn_global_load_lds(
        (const __attribute__((address_space(1))) void*)g,
        (__attribute__((address_space(3))) void*)l, 16, 0, 0);
}

// ---------------------------------------------------------------------------
// Kernel 1: quantize fp32 NCHW -> int8 NHWC' (permuted c), borders inline.
// Grid (58, N, 2): z splits the channel dim (32 c4-words each) -> 3712 small
// blocks, 7.4 KB LDS -> occupancy capped only by the 32-wave/CU limit; halves
// the per-block serial chain vs R5. Same shfl 4x4 byte transpose + single
// conflict-free ds_write_b32 (stride-33 u32).
// ---------------------------------------------------------------------------
__global__ __launch_bounds__(256) void quant_kernel(const float* __restrict__ x,
                                                    int8_t* __restrict__ xpad) {
    __shared__ uint32_t ldsu[W_IN * 33];           // 7,392 B
    const int hp = blockIdx.x, n = blockIdx.y, z = blockIdx.z;
    const int t = threadIdx.x;
    int8_t* row = xpad + ((size_t)n * H_PAD + hp) * W_PAD * C_IN;

    if (hp == 0 || hp == H_PAD - 1) {
        // zero this z's half of the padded row: 7424 B = 464 x 16B
        #pragma unroll
        for (int i = 0; i < 2; ++i) {
            int idx = i * 256 + t;
            if (idx < 464) *(int4*)(row + z * 7424 + idx * 16) = (int4){0, 0, 0, 0};
        }
        return;
    }
    const int h = hp - 1;
    const float* xp = x + (size_t)n * C_IN * H_IN * W_IN + (size_t)h * W_IN;

    const int wv = t >> 6, lane = t & 63;
    const int j = lane >> 4, w4 = lane & 15;
    const int w4c = (w4 < 14) ? w4 : 13;           // clamp; only store is masked
    const float* base = xp + (size_t)(64 * j) * (H_IN * W_IN) + w4c * 4;

    // batch-issue 8 independent float4 loads (kept in flight together)
    float4 v[8];
    #pragma unroll
    for (int it = 0; it < 8; ++it) {
        const int c4 = 32 * z + it * 4 + wv;
        v[it] = *(const float4*)(base + (size_t)c4 * (H_IN * W_IN));
    }
    #pragma unroll
    for (int it = 0; it < 8; ++it) {
        const int c4l = it * 4 + wv;               // local word index 0..31
        float f[4] = {v[it].x, v[it].y, v[it].z, v[it].w};
        uint32_t u = 0;
        #pragma unroll
        for (int i = 0; i < 4; ++i) {
            float qv = rintf(f[i] * 20.0f);         // ~= x/0.05, see R4 notes
            qv = fminf(fmaxf(qv, -128.0f), 127.0f);
            u |= ((uint32_t)((int)qv & 255)) << (8 * i);  // byte i = w-offset i
        }
        // 4x4 byte transpose across lanes {j, same w4}
        uint32_t p1 = __shfl_xor(u, 16);
        uint32_t tt = (j & 1) ? (((p1 >> 8) & 0x00FF00FFu) | (u & 0xFF00FF00u))
                              : ((u & 0x00FF00FFu) | ((p1 << 8) & 0xFF00FF00u));
        uint32_t p2 = __shfl_xor(tt, 32);
        uint32_t rr = (j & 2) ? ((p2 >> 16) | (tt & 0xFFFF0000u))
                              : ((tt & 0x0000FFFFu) | (p2 << 16));
        // lane now holds w = 4*w4 + j, stored words 32z+c4l (orig ch 4*(32z+c4l)... permuted)
        if (w4 < 14) ldsu[(w4 * 4 + j) * 33 + c4l] = rr;
    }
    // zero this z's half of border pixels w_p=0 and w_p=57 (16 x 16B)
    if (t < 16) {
        int pix = t >> 3;                          // 0 -> w_p 0, 1 -> w_p 57
        int8_t* p = row + (size_t)pix * (W_PAD - 1) * C_IN + z * 128 + (t & 7) * 16;
        *(int4*)p = (int4){0, 0, 0, 0};
    }
    __syncthreads();

    // Phase B: write x_pad[n][hp][w+1][32z..32z+32), 128B segments, coalesced
    int8_t* op = row + C_IN + z * 128;             // w_p starts at 1
    #pragma unroll
    for (int it = 0; it < 7; ++it) {               // 56 w * 32 c4l = 1792
        int idx = it * 256 + t;
        int w = idx >> 5, c4l = idx & 31;
        *(uint32_t*)(op + (size_t)w * C_IN + c4l * 4) = ldsu[w * 33 + c4l];
    }
}

// ---------------------------------------------------------------------------
// Kernel 2: repack weights fp32 [co][ci][kh][kw] -> int8 wq[khw][co][ci']
// with ci' permuted to match the activation layout: orig ci = 64*(p&3)+(p>>2)
// ---------------------------------------------------------------------------
__global__ __launch_bounds__(256) void wq_kernel(const float* __restrict__ w,
                                                 int8_t* __restrict__ wq) {
    int idx = blockIdx.x * 256 + threadIdx.x;   // < 9*256*256 = 589824
    int p   = idx & 255;
    int co  = (idx >> 8) & 255;
    int khw = idx >> 16;
    int ci  = 64 * (p & 3) + (p >> 2);          // sigma(p)
    float v = w[(size_t)(co * C_IN + ci) * 9 + khw];
    wq[idx] = (int8_t)(int)rintf(v);
}

// ---------------------------------------------------------------------------
// Kernel 3: implicit-GEMM conv via v_mfma_i32_16x16x64_i8, fat wave tiles.
// Block 128 thr = 2 waves; block tile 128co x 64sp; wave tile 64co x 64sp
// (4x4 accs). Per K-64 step: 4 A-reads + 4 B-reads -> 16 MFMAs (2 MFMA per
// ds_read_b128, 3x the reuse of R6). Grid 392 x 2 = 784 blocks, 48 KB LDS
// -> 3 blocks/CU. 9 stages (one 3x3 tap, BK=256): W 32KB (16 glds passes) +
// Act 16KB (8 passes), XOR chunk swizzle (row-parity term folded into two
// precomputed base pointers).
// A/B-op: m/n = lane&15, k-chunk = ks*4 + (lane>>4).
// C/D: col(sp) = lane&15, row(co) = (lane>>4)*4 + reg   [verified, R1-R4]
// ---------------------------------------------------------------------------
__global__ __launch_bounds__(128) void conv_kernel(const int8_t* __restrict__ xpad,
                                                   const int8_t* __restrict__ wq,
                                                   float* __restrict__ out) {
    __shared__ __align__(16) int8_t lds[49152];  // W: [0,32768) Act: [32768,49152)
    const int t = threadIdx.x;                   // 0..127
    const int wave = t >> 6, lane = t & 63;
    const int q = lane >> 4, s = lane & 15;
    const int co_blk = blockIdx.y * 128;
    const int sp_blk = blockIdx.x * 64;

    // ---- staging decode ----
    // pass p: flat offset o = p*2048 + t*16 ; row_l = p*8 + (t>>4);
    // stored chunk = t&15 ; source chunk = (t&15) ^ (row_l&15) = ch0 ^ 8*(p&1)
    const int rl  = t >> 4;                       // 0..7
    const int ch0 = (t & 15) ^ rl;
    const int8_t* gwE = wq + (size_t)(co_blk + rl) * 256 + ch0 * 16;
    const int8_t* gwO = wq + (size_t)(co_blk + rl) * 256 + (ch0 ^ 8) * 16;

    int aofs[8];                                  // act offsets (E/O parity baked in)
    #pragma unroll
    for (int p = 0; p < 8; ++p) {
        int sp = sp_blk + p * 8 + rl;
        int n  = sp / (H_OUT * W_OUT);
        int rm = sp - n * (H_OUT * W_OUT);
        int ho = rm / W_OUT;
        int wo = rm - ho * W_OUT;
        aofs[p] = ((n * H_PAD + ho * 2) * W_PAD + wo * 2) * C_IN
                + (ch0 ^ (8 * (p & 1))) * 16;
    }

    // ---- output mapping ----
    int out_base[4];
    #pragma unroll
    for (int jj = 0; jj < 4; ++jj) {
        int sp = sp_blk + jj * 16 + s;
        int n  = sp / (H_OUT * W_OUT);
        int rm = sp - n * (H_OUT * W_OUT);
        int ho = rm / W_OUT;
        int wo = rm - ho * W_OUT;
        out_base[jj] = n * (C_OUT * H_OUT * W_OUT) + ho * W_OUT + wo;
    }
    const int cw = wave * 64;                     // wave co base within block

    v4i acc[4][4];
    #pragma unroll
    for (int i = 0; i < 4; ++i)
        #pragma unroll
        for (int jj = 0; jj < 4; ++jj)
            acc[i][jj] = (v4i){0, 0, 0, 0};

    // ---- K loop: 9 stages (one tap each) ----
    for (int kh = 0; kh < 3; ++kh) {
        for (int kwv = 0; kwv < 3; ++kwv) {
            __syncthreads();                       // all waves done reading prev stage
            const int woff = (kh * 3 + kwv) * (C_OUT * C_IN);
            const int aoff = (kh * W_PAD + kwv) * C_IN;
            #pragma unroll
            for (int p = 0; p < 16; ++p)           // W: 128 rows x 256B = 32KB
                glds16(((p & 1) ? gwO : gwE) + woff + p * 2048,
                       lds + p * 2048 + t * 16);
            #pragma unroll
            for (int p = 0; p < 8; ++p)            // Act: 64 rows x 256B = 16KB
                glds16(xpad + aofs[p] + aoff,
                       lds + 32768 + p * 2048 + t * 16);
            __syncthreads();                       // vmcnt(0) drain: LDS ready

            #pragma unroll
            for (int ks = 0; ks < 4; ++ks) {       // k = 64 bytes per step
                const int st = ((ks * 4 + q) ^ s) * 16;   // swizzled chunk offset
                v4i a[4], b[4];
                #pragma unroll
                for (int i = 0; i < 4; ++i)
                    a[i] = *(const v4i*)(lds + (cw + i * 16 + s) * 256 + st);
                #pragma unroll
                for (int jj = 0; jj < 4; ++jj)
                    b[jj] = *(const v4i*)(lds + 32768 + (jj * 16 + s) * 256 + st);
                #pragma unroll
                for (int i = 0; i < 4; ++i)
                    #pragma unroll
                    for (int jj = 0; jj < 4; ++jj)
                        acc[i][jj] = __builtin_amdgcn_mfma_i32_16x16x64_i8(
                            a[i], b[jj], acc[i][jj], 0, 0, 0);
            }
        }
    }

    // ---- epilogue: coalesced dword stores (lanes 0-15 = consecutive sp) ----
    #pragma unroll
    for (int jj = 0; jj < 4; ++jj) {
        #pragma unroll
        for (int i = 0; i < 4; ++i) {
            const int co0 = co_blk + cw + i * 16 + q * 4;
            #pragma unroll
            for (int r = 0; r < 4; ++r) {
                out[(size_t)out_base[jj] + (size_t)(co0 + r) * (H_OUT * W_OUT)] =
                    (float)acc[i][jj][r] * 0.0005f;
            }
        }
    }
}

// ---------------------------------------------------------------------------
extern "C" void kernel_launch(void* const* d_in, const int* in_sizes, int n_in,
                              void* d_out, int out_size, void* d_ws, size_t ws_size,
                              hipStream_t stream) {
    const float* x = (const float*)d_in[0];
    const float* w = (const float*)d_in[1];
    float* out = (float*)d_out;
    int8_t* xpad = (int8_t*)d_ws;
    int8_t* wqb  = xpad + XPAD_BYTES;

    quant_kernel<<<dim3(H_PAD, N_IMG, 2), 256, 0, stream>>>(x, xpad);
    wq_kernel<<<(9 * C_OUT * C_IN) / 256, 256, 0, stream>>>(w, wqb);
    conv_kernel<<<dim3(SP_TOT / 64, C_OUT / 128), 128, 0, stream>>>(xpad, wqb, out);
}

// Round 8
// 190.405 us; speedup vs baseline: 1.0274x; 1.0274x over previous
//
#include <hip/hip_runtime.h>
#include <stdint.h>

typedef int v4i __attribute__((ext_vector_type(4)));

// Problem dims
#define N_IMG 32
#define C_IN 256
#define H_IN 56
#define W_IN 56
#define C_OUT 256
#define H_OUT 28
#define W_OUT 28
#define H_PAD 58
#define W_PAD 58
#define SP_TOT (N_IMG*H_OUT*W_OUT)   // 25088

#define XPAD_BYTES ((size_t)N_IMG*H_PAD*W_PAD*C_IN)   // 27,557,888 (16B aligned)

// Activations stored in NATURAL channel order (sigma = identity this round).

__device__ __forceinline__ void glds16(const int8_t* g, int8_t* l) {
    __builtin_amdgcn_global_load_lds(
        (const __attribute__((address_space(1))) void*)g,
        (__attribute__((address_space(3))) void*)l, 16, 0, 0);
}

// ---------------------------------------------------------------------------
// Kernel 1: quantize fp32 NCHW -> int8 NHWC, borders inline.
// Grid (58, N), 256 thr. Phase A: stage the whole fp32 row (56x256 floats,
// 57344B) into LDS via 14 queued global_load_lds dwordx4 per thread (DMA
// queue holds all 14 in flight -> one latency, no VGPR pressure). Chunk
// (c, w4) lives at LDS 16B-index c*14+w4. Phase B: lane (j,w4) reads float4
// (channel 4c4'+j, w=4w4..+3) -- bank-group (6j+w4)%8 = exactly 8 lanes per
// 4-bank group = conflict-free-equivalent b128 -- quantizes (x*20, rint,
// clamp), 2-step shfl_xor 4x4 byte transpose (verified R5), single
// conflict-free ds_write_b32 to stride-65 u32 stage. Phase B2: 256B/wave
// coalesced global writes.
// ---------------------------------------------------------------------------
__global__ __launch_bounds__(256) void quant_kernel(const float* __restrict__ x,
                                                    int8_t* __restrict__ xpad) {
    __shared__ __align__(16) int8_t lraw[57344];   // fp32 row, [c][w4] 16B chunks
    __shared__ uint32_t ldsu[W_IN * 65];           // 14,560 B out-stage
    const int hp = blockIdx.x, n = blockIdx.y;
    const int t = threadIdx.x;
    int8_t* row = xpad + ((size_t)n * H_PAD + hp) * W_PAD * C_IN;

    if (hp == 0 || hp == H_PAD - 1) {
        // zero full padded row: 58*256 B = 928 x 16B
        #pragma unroll
        for (int i = 0; i < 4; ++i) {
            int idx = i * 256 + t;
            if (idx < 928) *(int4*)(row + idx * 16) = (int4){0, 0, 0, 0};
        }
        return;
    }
    const int h = hp - 1;
    const float* xrow = x + (size_t)n * (C_IN * H_IN * W_IN) + (size_t)h * W_IN;

    // ---- Phase A: DMA-stage 57344B of fp32 into LDS (14 in flight) ----
    #pragma unroll
    for (int p = 0; p < 14; ++p) {
        const int k = p * 256 + t;                 // 16B chunk index 0..3583
        const int c = k / 14, w4 = k - c * 14;
        glds16((const int8_t*)(xrow + (size_t)c * (H_IN * W_IN) + w4 * 4),
               lraw + k * 16);
    }
    // zero border pixels w_p = 0 and w_p = 57 (32 x 16B) while DMA runs
    if (t < 32) {
        int8_t* p = (t < 16) ? (row + t * 16)
                             : (row + (size_t)(W_PAD - 1) * C_IN + (t - 16) * 16);
        *(int4*)p = (int4){0, 0, 0, 0};
    }
    __syncthreads();                               // drains vmcnt: lraw ready

    // ---- Phase B: quantize + 4x4 shfl byte transpose -> ldsu ----
    const int lane = t & 63, wv = t >> 6;
    const int j = lane >> 4, w4 = lane & 15;
    const int w4c = (w4 < 14) ? w4 : 13;           // clamp reads; store masked
    #pragma unroll
    for (int i16 = 0; i16 < 16; ++i16) {
        const int c4p = i16 * 4 + wv;              // output word index 0..63
        const float4 v = *(const float4*)(lraw + ((4 * c4p + j) * 14 + w4c) * 16);
        float f[4] = {v.x, v.y, v.z, v.w};
        uint32_t u = 0;
        #pragma unroll
        for (int i = 0; i < 4; ++i) {
            float qv = rintf(f[i] * 20.0f);        // ~= x/0.05, see R4 notes
            qv = fminf(fmaxf(qv, -128.0f), 127.0f);
            u |= ((uint32_t)((int)qv & 255)) << (8 * i);  // byte i = w-offset i
        }
        // 4x4 byte transpose across lanes {j, same w4}  [verified R5]
        uint32_t p1 = __shfl_xor(u, 16);
        uint32_t tt = (j & 1) ? (((p1 >> 8) & 0x00FF00FFu) | (u & 0xFF00FF00u))
                              : ((u & 0x00FF00FFu) | ((p1 << 8) & 0xFF00FF00u));
        uint32_t p2 = __shfl_xor(tt, 32);
        uint32_t rr = (j & 2) ? ((p2 >> 16) | (tt & 0xFFFF0000u))
                              : ((tt & 0x0000FFFFu) | (p2 << 16));
        // lane now holds w = 4*w4 + j, channels 4*c4p .. 4*c4p+3 (natural order)
        if (w4 < 14) ldsu[(w4 * 4 + j) * 65 + c4p] = rr;
    }
    __syncthreads();

    // ---- Phase B2: write x_pad[n][hp][w+1][c], 256B/wave coalesced ----
    int8_t* op = row + C_IN;                       // w_p starts at 1
    #pragma unroll
    for (int it = 0; it < 14; ++it) {              // 56 w * 64 c4 = 3584
        int idx = it * 256 + t;
        int w = idx >> 6, c4 = idx & 63;
        *(uint32_t*)(op + (size_t)w * C_IN + c4 * 4) = ldsu[w * 65 + c4];
    }
}

// ---------------------------------------------------------------------------
// Kernel 2: repack weights fp32 [co][ci][kh][kw] -> int8 wq[khw][co][ci]
// (natural ci order -- matches this round's activation layout)
// ---------------------------------------------------------------------------
__global__ __launch_bounds__(256) void wq_kernel(const float* __restrict__ w,
                                                 int8_t* __restrict__ wq) {
    int idx = blockIdx.x * 256 + threadIdx.x;   // < 9*256*256 = 589824
    int ci  = idx & 255;
    int co  = (idx >> 8) & 255;
    int khw = idx >> 16;
    float v = w[(size_t)(co * C_IN + ci) * 9 + khw];
    wq[idx] = (int8_t)(int)rintf(v);
}

// ---------------------------------------------------------------------------
// Kernel 3: implicit-GEMM conv, LDS-staged -- reverted to the R3 structure
// (best measured ~29us: 32KB LDS -> 5 blocks/CU, 20 waves/CU wins over
// fatter tiles). Tile 64co x 64sp, 256 thr = 4 waves of 32co x 32sp ->
// grid 392 x 4. 9 stages (one 3x3 tap, BK=256): 8 glds16/thread
// (W 16KB + Act 16KB), XOR chunk swizzle; per wave 16 ds_read_b128 +
// 16 MFMA between barriers.
// C/D: col(sp) = s, row(co) = q*4 + reg   [verified mapping]
// ---------------------------------------------------------------------------
__global__ __launch_bounds__(256) void conv_kernel(const int8_t* __restrict__ xpad,
                                                   const int8_t* __restrict__ wq,
                                                   float* __restrict__ out) {
    __shared__ __align__(16) int8_t lds[32768];  // W: [0,16384) Act: [16384,32768)
    const int t = threadIdx.x;
    const int wave = t >> 6, lane = t & 63;
    const int q = lane >> 4, s = lane & 15;
    const int co_blk = blockIdx.y * 64;
    const int sp_blk = blockIdx.x * 64;

    // ---- staging decode (fixed per thread) ----
    const int rl   = t >> 4;                      // row_l for r=0 (0..15)
    const int chunk = (t & 15) ^ (rl & 15);
    const int8_t* gw = wq + (size_t)(co_blk + rl) * 256 + chunk * 16;

    const int8_t* ga[4];
    #pragma unroll
    for (int r = 0; r < 4; ++r) {
        int sp = sp_blk + r * 16 + rl;
        int n  = sp / (H_OUT * W_OUT);
        int rm = sp - n * (H_OUT * W_OUT);
        int ho = rm / W_OUT;
        int wo = rm - ho * W_OUT;
        ga[r] = xpad + ((size_t)(n * H_PAD + ho * 2) * W_PAD + wo * 2) * C_IN + chunk * 16;
    }

    // ---- output mapping ----
    const int cw = (wave >> 1) * 32;          // LDS-local co base of this wave
    const int sw = (wave & 1) * 32;           // LDS-local sp base of this wave
    int out_base[2];
    #pragma unroll
    for (int jj = 0; jj < 2; ++jj) {
        int sp = sp_blk + sw + jj * 16 + s;
        int n  = sp / (H_OUT * W_OUT);
        int rm = sp - n * (H_OUT * W_OUT);
        int ho = rm / W_OUT;
        int wo = rm - ho * W_OUT;
        out_base[jj] = n * (C_OUT * H_OUT * W_OUT) + ho * W_OUT + wo;
    }

    v4i acc[2][2];
    #pragma unroll
    for (int i = 0; i < 2; ++i)
        #pragma unroll
        for (int jj = 0; jj < 2; ++jj)
            acc[i][jj] = (v4i){0, 0, 0, 0};

    // ---- K loop: 9 stages (one tap each) ----
    for (int kh = 0; kh < 3; ++kh) {
        for (int kwv = 0; kwv < 3; ++kwv) {
            __syncthreads();                       // all waves done reading prev stage
            const int woff = (kh * 3 + kwv) * (C_OUT * C_IN);
            const int aoff = (kh * W_PAD + kwv) * C_IN;
            #pragma unroll
            for (int r = 0; r < 4; ++r)
                glds16(gw + woff + r * 4096, lds + r * 4096 + t * 16);
            #pragma unroll
            for (int r = 0; r < 4; ++r)
                glds16(ga[r] + aoff, lds + 16384 + r * 4096 + t * 16);
            __syncthreads();                       // vmcnt(0) drain: LDS ready

            #pragma unroll
            for (int ks = 0; ks < 4; ++ks) {
                const int st = ((ks * 4 + q) ^ s) * 16;   // swizzled chunk offset
                v4i a[2], b[2];
                #pragma unroll
                for (int i = 0; i < 2; ++i)
                    a[i] = *(const v4i*)(lds + (cw + i * 16 + s) * 256 + st);
                #pragma unroll
                for (int jj = 0; jj < 2; ++jj)
                    b[jj] = *(const v4i*)(lds + 16384 + (sw + jj * 16 + s) * 256 + st);
                #pragma unroll
                for (int i = 0; i < 2; ++i)
                    #pragma unroll
                    for (int jj = 0; jj < 2; ++jj)
                        acc[i][jj] = __builtin_amdgcn_mfma_i32_16x16x64_i8(
                            a[i], b[jj], acc[i][jj], 0, 0, 0);
            }
        }
    }

    // ---- epilogue: coalesced dword stores (lanes 0-15 = consecutive sp) ----
    #pragma unroll
    for (int jj = 0; jj < 2; ++jj) {
        #pragma unroll
        for (int i = 0; i < 2; ++i) {
            const int co0 = co_blk + cw + i * 16 + q * 4;
            #pragma unroll
            for (int r = 0; r < 4; ++r) {
                out[(size_t)out_base[jj] + (size_t)(co0 + r) * (H_OUT * W_OUT)] =
                    (float)acc[i][jj][r] * 0.0005f;
            }
        }
    }
}

// ---------------------------------------------------------------------------
extern "C" void kernel_launch(void* const* d_in, const int* in_sizes, int n_in,
                              void* d_out, int out_size, void* d_ws, size_t ws_size,
                              hipStream_t stream) {
    const float* x = (const float*)d_in[0];
    const float* w = (const float*)d_in[1];
    float* out = (float*)d_out;
    int8_t* xpad = (int8_t*)d_ws;
    int8_t* wqb  = xpad + XPAD_BYTES;

    quant_kernel<<<dim3(H_PAD, N_IMG), 256, 0, stream>>>(x, xpad);
    wq_kernel<<<(9 * C_OUT * C_IN) / 256, 256, 0, stream>>>(w, wqb);
    conv_kernel<<<dim3(SP_TOT / 64, C_OUT / 64), 256, 0, stream>>>(xpad, wqb, out);
}